// Round 5
// baseline (1262.626 us; speedup 1.0000x reference)
//
#include <hip/hip_runtime.h>

// SwinV2 block, MI355X. All heavy math in bf16 MFMA (f32 accum).
// Pipeline: cvt(x) -> wT x4 -> cpb -> GEMM qkv -> attn -> GEMM proj+LN1 ->
//           GEMM fc1(gelu) -> GEMM fc2+LN2 -> d_out (f32).
// R4 (2-phase LDS pipeline) = 927us. R5 (deep pipe) / R6 (MLP fusion) both
// REGRESSED via occupancy loss + barrier lockstep.
// R7: BARRIER-FREE REG-STREAMING GEMMs. K is tiny (256/1024) and weights are
//     L2-resident, so LDS staging buys nothing: load A and B fragments
//     directly to registers (same addresses the ds_reads produced), 2-buffer
//     rotation, no barriers, no LDS in the loop. Stalls are per-wave, not
//     per-block; L1/L2 dedups cross-wave fragment overlap.

#define TOKS 131072            // B * H * W
#define LOGIT_MAX 4.60517018598809136804f

typedef __attribute__((ext_vector_type(8))) short short8;
typedef __attribute__((ext_vector_type(4))) float f32x4;

__device__ __forceinline__ float b2f(unsigned short s) {
    union { unsigned int u; float f; } x; x.u = ((unsigned int)s) << 16; return x.f;
}
__device__ __forceinline__ unsigned short f2b(float f) {
    union { float f; unsigned int u; } x; x.f = f;
    unsigned int r = x.u + 0x7fffu + ((x.u >> 16) & 1u);  // RNE
    return (unsigned short)(r >> 16);
}

#define MFMA16(a, b, c) __builtin_amdgcn_mfma_f32_16x16x32_bf16((a), (b), (c), 0, 0, 0)

// ---------------- prep kernels ----------------

__global__ __launch_bounds__(256) void cvt_kernel(const float* __restrict__ in,
                                                  unsigned short* __restrict__ out, int n) {
    int i = (blockIdx.x * 256 + threadIdx.x) * 4;
    if (i >= n) return;
    float4 v = *(const float4*)(in + i);
    ushort4 o;
    o.x = f2b(v.x); o.y = f2b(v.y); o.z = f2b(v.z); o.w = f2b(v.w);
    *(ushort4*)(out + i) = o;
}

// dst[n*K + k] = bf16(src[k*N + n])   (src is K x N row-major, dst is N x K)
__global__ __launch_bounds__(256) void wt_kernel(const float* __restrict__ src,
                                                 unsigned short* __restrict__ dst,
                                                 int K, int N) {
    int idx = blockIdx.x * 256 + threadIdx.x;
    if (idx >= K * N) return;
    int n = idx / K, k = idx - n * K;
    dst[idx] = f2b(src[(size_t)k * N + n]);
}

__device__ __forceinline__ float cpb_coord(int d) {
    float t = (float)d * (8.0f / 7.0f);
    float a = log2f(fabsf(t) + 1.0f) * (1.0f / 3.0f);   // log2(8)=3
    return t < 0.0f ? -a : a;
}

// biasT[h][i][j] = 16*sigmoid( cpb_mlp(rel_coords(i,j))[h] );  qkv_bias[768]
__global__ __launch_bounds__(256) void cpb_kernel(
    const float* __restrict__ w1, const float* __restrict__ b1, const float* __restrict__ w2,
    const float* __restrict__ qb, const float* __restrict__ vb,
    float* __restrict__ biasT, float* __restrict__ qkv_bias)
{
    __shared__ float tbl[225];
    int h = blockIdx.x, t = threadIdx.x;
    if (t < 225) {
        float r0 = cpb_coord(t / 15 - 7), r1 = cpb_coord(t % 15 - 7);
        float acc = 0.f;
        for (int j = 0; j < 512; ++j) {
            float hid = fmaxf(r0 * w1[j] + r1 * w1[512 + j] + b1[j], 0.f);
            acc += hid * w2[j * 8 + h];
        }
        tbl[t] = acc;
    }
    __syncthreads();
    for (int o = t; o < 4096; o += 256) {
        int i = o >> 6, j = o & 63;
        int idx = ((i >> 3) - (j >> 3) + 7) * 15 + ((i & 7) - (j & 7) + 7);
        biasT[h * 4096 + o] = 16.0f / (1.0f + __expf(-tbl[idx]));
    }
    if (h == 0)
        for (int n = t; n < 768; n += 256)
            qkv_bias[n] = n < 256 ? qb[n] : (n < 512 ? 0.f : vb[n - 512]);
}

// ---------------- barrier-free reg-streaming GEMM: C = A(MxK)*Bt(NxK)^T + bias ----
// 128x128 tile, 4 waves 2x2, wave = 64x64. No LDS, no barriers: A/B fragments
// loaded straight to registers (16B/lane, 16-row x 64B coalesced segments),
// 2-buffer rotation (~1.5-step lookahead, compiler hoists further).
// EPI 0: bf16 row-major out.  EPI 1: qkv scatter.  EPI 2: fast gelu.
template<int EPI, int GX, int KT>
__global__ __launch_bounds__(256) void gemm_bt(
    const unsigned short* __restrict__ A, const unsigned short* __restrict__ Bt,
    const float* __restrict__ bias, unsigned short* __restrict__ out, int N)
{
    constexpr int NT = KT >> 5;          // k-steps (8 or 32)
    const int tid = threadIdx.x;
    const int lane = tid & 63;
    const int wave = tid >> 6;
    const int wm = (wave >> 1) * 64, wn = (wave & 1) * 64;
    // XCD-bijective swizzle: n-blocks sharing A rows land on the same XCD L2.
    const int nwg = GX * (int)gridDim.y;
    int flat = (int)(blockIdx.y * GX + blockIdx.x);
    flat = (flat & 7) * (nwg >> 3) + (flat >> 3);
    const int bx = flat % GX;
    const int by = flat / GX;
    const int m0 = by * 128, n0 = bx * 128;
    const int l15 = lane & 15, lq = lane >> 4;

    const unsigned short* pA[4];
    const unsigned short* pB[4];
    #pragma unroll
    for (int f = 0; f < 4; ++f) {
        pA[f] = A + (size_t)(m0 + wm + f * 16 + l15) * KT + lq * 8;
        pB[f] = Bt + (size_t)(n0 + wn + f * 16 + l15) * KT + lq * 8;
    }

    short8 a0[4], b0[4], a1[4], b1[4];
    #pragma unroll
    for (int f = 0; f < 4; ++f) {
        a0[f] = *(const short8*)(pA[f]);      b0[f] = *(const short8*)(pB[f]);
        a1[f] = *(const short8*)(pA[f] + 32); b1[f] = *(const short8*)(pB[f] + 32);
    }

    f32x4 acc[4][4] = {};
    auto mfmas = [&](short8 (&a)[4], short8 (&b)[4]) {
        #pragma unroll
        for (int tm = 0; tm < 4; ++tm)
            #pragma unroll
            for (int tn = 0; tn < 4; ++tn)
                acc[tm][tn] = MFMA16(a[tm], b[tn], acc[tm][tn]);
    };

    #pragma unroll 1
    for (int t = 0; t < NT; t += 2) {
        mfmas(a0, b0);
        if (t + 2 < NT) {
            #pragma unroll
            for (int f = 0; f < 4; ++f) {
                a0[f] = *(const short8*)(pA[f] + 64);
                b0[f] = *(const short8*)(pB[f] + 64);
            }
        }
        mfmas(a1, b1);
        if (t + 3 < NT) {
            #pragma unroll
            for (int f = 0; f < 4; ++f) {
                a1[f] = *(const short8*)(pA[f] + 96);
                b1[f] = *(const short8*)(pB[f] + 96);
            }
        }
        #pragma unroll
        for (int f = 0; f < 4; ++f) { pA[f] += 64; pB[f] += 64; }
    }

    float bv[4];
    #pragma unroll
    for (int tn = 0; tn < 4; ++tn) bv[tn] = bias[n0 + wn + tn * 16 + l15];

    #pragma unroll
    for (int tm = 0; tm < 4; ++tm)
        #pragma unroll
        for (int tn = 0; tn < 4; ++tn)
            #pragma unroll
            for (int r = 0; r < 4; ++r) {
                int gm = m0 + wm + tm * 16 + lq * 4 + r;
                int gn = n0 + wn + tn * 16 + l15;
                float v = acc[tm][tn][r] + bv[tn];
                if constexpr (EPI == 2) {
                    // gelu(v) ~= v * sigmoid(1.59577v + 0.0713548 v^3); |err|<~1e-3
                    float e = __expf(v * fmaf(-0.0713548162972754f, v * v,
                                              -1.5957691216057308f));
                    v = v * __builtin_amdgcn_rcpf(1.0f + e);
                }
                if constexpr (EPI == 1) {
                    int s = gn >> 8, hd = gn & 255;
                    out[((size_t)(s * 8 + (hd >> 5)) * TOKS + gm) * 32 + (hd & 31)] = f2b(v);
                } else {
                    out[(size_t)gm * N + gn] = f2b(v);
                }
            }
}

// ---------------- reg-streaming GEMM + LayerNorm + residual ----------------
// 64x256 tile (full channel row), 4 waves 1x4. Barrier-free K-loop; LDS only
// for the tiny cross-wave LN reduction (2KB).
// MODE 1: outb = bf16( residf_f32 + LN(A@Bt^T + bias) )   (x1 = x + LN(proj))
// MODE 2: outf = f32(residb_bf16) + LN(A@Bt^T + bias)     (d_out = x1 + LN(h2))
template<int MODE, int KT>
__global__ __launch_bounds__(256) void gemm_ln(
    const unsigned short* __restrict__ A, const unsigned short* __restrict__ Bt,
    const float* __restrict__ bias,
    const float* __restrict__ residf, const unsigned short* __restrict__ residb,
    const float* __restrict__ lng, const float* __restrict__ lnb,
    unsigned short* __restrict__ outb, float* __restrict__ outf)
{
    constexpr int NT = KT >> 5;
    __shared__ float sums[256];   // [row][wave]
    __shared__ float sqs[256];
    const int tid = threadIdx.x;
    const int lane = tid & 63;
    const int wave = tid >> 6;
    const int wn = wave * 64;
    const int m0 = blockIdx.x * 64;
    const int l15 = lane & 15, lq = lane >> 4;

    const unsigned short* pA[4];
    const unsigned short* pB[4];
    #pragma unroll
    for (int f = 0; f < 4; ++f) {
        pA[f] = A + (size_t)(m0 + f * 16 + l15) * KT + lq * 8;
        pB[f] = Bt + (size_t)(wn + f * 16 + l15) * KT + lq * 8;
    }

    short8 a0[4], b0[4], a1[4], b1[4];
    #pragma unroll
    for (int f = 0; f < 4; ++f) {
        a0[f] = *(const short8*)(pA[f]);      b0[f] = *(const short8*)(pB[f]);
        a1[f] = *(const short8*)(pA[f] + 32); b1[f] = *(const short8*)(pB[f] + 32);
    }

    f32x4 acc[4][4] = {};
    auto mfmas = [&](short8 (&a)[4], short8 (&b)[4]) {
        #pragma unroll
        for (int tm = 0; tm < 4; ++tm)
            #pragma unroll
            for (int tn = 0; tn < 4; ++tn)
                acc[tm][tn] = MFMA16(a[tm], b[tn], acc[tm][tn]);
    };

    #pragma unroll 1
    for (int t = 0; t < NT; t += 2) {
        mfmas(a0, b0);
        if (t + 2 < NT) {
            #pragma unroll
            for (int f = 0; f < 4; ++f) {
                a0[f] = *(const short8*)(pA[f] + 64);
                b0[f] = *(const short8*)(pB[f] + 64);
            }
        }
        mfmas(a1, b1);
        if (t + 3 < NT) {
            #pragma unroll
            for (int f = 0; f < 4; ++f) {
                a1[f] = *(const short8*)(pA[f] + 96);
                b1[f] = *(const short8*)(pB[f] + 96);
            }
        }
        #pragma unroll
        for (int f = 0; f < 4; ++f) { pA[f] += 64; pB[f] += 64; }
    }

    float bv[4], gv[4], ev[4];
    #pragma unroll
    for (int tn = 0; tn < 4; ++tn) {
        int gn = wn + tn * 16 + l15;
        bv[tn] = bias[gn]; gv[tn] = lng[gn]; ev[tn] = lnb[gn];
    }

    // cross-wave row sums via LDS
    #pragma unroll
    for (int tm = 0; tm < 4; ++tm)
        #pragma unroll
        for (int r = 0; r < 4; ++r) {
            int rl = tm * 16 + lq * 4 + r;
            float s = 0.f, q = 0.f;
            #pragma unroll
            for (int tn = 0; tn < 4; ++tn) {
                float v = acc[tm][tn][r] + bv[tn];
                s += v; q += v * v;
            }
            #pragma unroll
            for (int o = 1; o < 16; o <<= 1) { s += __shfl_xor(s, o); q += __shfl_xor(q, o); }
            if (l15 == 0) { sums[rl * 4 + wave] = s; sqs[rl * 4 + wave] = q; }
        }
    __syncthreads();

    #pragma unroll
    for (int tm = 0; tm < 4; ++tm)
        #pragma unroll
        for (int r = 0; r < 4; ++r) {
            int rl = tm * 16 + lq * 4 + r;
            float s = sums[rl * 4] + sums[rl * 4 + 1] + sums[rl * 4 + 2] + sums[rl * 4 + 3];
            float q = sqs[rl * 4] + sqs[rl * 4 + 1] + sqs[rl * 4 + 2] + sqs[rl * 4 + 3];
            float mu = s * (1.0f / 256.0f);
            float rs = rsqrtf(q * (1.0f / 256.0f) - mu * mu + 1e-5f);
            size_t rowo = (size_t)(m0 + rl) * 256;
            #pragma unroll
            for (int tn = 0; tn < 4; ++tn) {
                int gn = wn + tn * 16 + l15;
                float v = acc[tm][tn][r] + bv[tn];
                float nv = (v - mu) * rs * gv[tn] + ev[tn];
                if constexpr (MODE == 1)
                    outb[rowo + gn] = f2b(residf[rowo + gn] + nv);
                else
                    outf[rowo + gn] = b2f(residb[rowo + gn]) + nv;
            }
        }
}

// ---------------- attention: one wave per (window, head) ----------------

__device__ __forceinline__ int regid(int wy, int wx, int t) {
    int y = wy * 8 + (t >> 3), x = wx * 8 + (t & 7);
    int ry = (y < 56) ? 0 : (y < 60 ? 1 : 2);
    int rx = (x < 56) ? 0 : (x < 60 ? 1 : 2);
    return ry * 3 + rx;
}

__device__ __forceinline__ void load_norm(const unsigned short* __restrict__ p,
                                          unsigned short* __restrict__ dst, int lane) {
    union U { uint4 u; unsigned short s[8]; };
    U ld[4];
    #pragma unroll
    for (int c = 0; c < 4; ++c) ld[c].u = *(const uint4*)(p + c * 8);
    float f[32]; float ss = 0.f;
    #pragma unroll
    for (int c = 0; c < 4; ++c)
        #pragma unroll
        for (int j = 0; j < 8; ++j) { float v = b2f(ld[c].s[j]); f[c * 8 + j] = v; ss += v * v; }
    float nrm = rsqrtf(fmaxf(ss, 1e-12f));
    #pragma unroll
    for (int c = 0; c < 4; ++c) {
        U st;
        #pragma unroll
        for (int j = 0; j < 8; ++j) st.s[j] = f2b(f[c * 8 + j] * nrm);
        *(uint4*)(dst + lane * 32 + c * 8) = st.u;
    }
}

__global__ __launch_bounds__(64) void attn_kernel(
    const unsigned short* __restrict__ qkv, const float* __restrict__ biasT,
    const float* __restrict__ ls, unsigned short* __restrict__ outb)
{
    __shared__ __align__(16) unsigned short sQ[64 * 32];
    __shared__ __align__(16) unsigned short sK[64 * 32];
    __shared__ __align__(16) unsigned short sV[64 * 32];
    __shared__ __align__(16) unsigned short sP[64 * 64];

    const int lane = threadIdx.x;
    const int h = blockIdx.x & 7;
    const int win = blockIdx.x >> 3;
    const int b = win >> 6;
    const int wy = (win >> 3) & 7, wx = win & 7;
    const int l15 = lane & 15, lq = lane >> 4;

    {   // staging: lane = window-token; gather through the cyclic shift (+4)
        int ty = lane >> 3, tx = lane & 7;
        int hh = (wy * 8 + ty + 4) & 63, ww = (wx * 8 + tx + 4) & 63;
        size_t tok = (size_t)b * 4096 + hh * 64 + ww;
        const size_t plane = (size_t)TOKS * 32;
        const unsigned short* qp = qkv + (size_t)h * plane + tok * 32;
        const unsigned short* kp = qkv + (size_t)(8 + h) * plane + tok * 32;
        const unsigned short* vp = qkv + (size_t)(16 + h) * plane + tok * 32;
        load_norm(qp, sQ, lane);
        load_norm(kp, sK, lane);
        #pragma unroll
        for (int c = 0; c < 4; ++c)
            *(uint4*)&sV[lane * 32 + c * 8] = *(const uint4*)(vp + c * 8);
    }
    __syncthreads();

    // QK^T: A = qhat (64x32), Bt = khat (64x32)
    short8 aQ[4], bK[4];
    #pragma unroll
    for (int t = 0; t < 4; ++t) {
        aQ[t] = *(const short8*)&sQ[(t * 16 + l15) * 32 + lq * 8];
        bK[t] = *(const short8*)&sK[(t * 16 + l15) * 32 + lq * 8];
    }
    f32x4 acc[4][4] = {};
    #pragma unroll
    for (int tm = 0; tm < 4; ++tm)
        #pragma unroll
        for (int tn = 0; tn < 4; ++tn)
            acc[tm][tn] = MFMA16(aQ[tm], bK[tn], acc[tm][tn]);

    float scale = __expf(fminf(ls[h], LOGIT_MAX));

    // scale + cpb-bias + shift-mask + softmax (rows: (lq,r,tm) fixed; cols: (tn,l15))
    #pragma unroll
    for (int tm = 0; tm < 4; ++tm)
        #pragma unroll
        for (int r = 0; r < 4; ++r) {
            int i = tm * 16 + lq * 4 + r;
            int ri = regid(wy, wx, i);
            float v[4];
            #pragma unroll
            for (int tn = 0; tn < 4; ++tn) {
                int j = tn * 16 + l15;
                float sc = acc[tm][tn][r] * scale + biasT[h * 4096 + i * 64 + j];
                if (ri != regid(wy, wx, j)) sc -= 100.f;
                v[tn] = sc;
            }
            float m = fmaxf(fmaxf(v[0], v[1]), fmaxf(v[2], v[3]));
            #pragma unroll
            for (int o = 1; o < 16; o <<= 1) m = fmaxf(m, __shfl_xor(m, o));
            float sum = 0.f;
            #pragma unroll
            for (int tn = 0; tn < 4; ++tn) { v[tn] = __expf(v[tn] - m); sum += v[tn]; }
            #pragma unroll
            for (int o = 1; o < 16; o <<= 1) sum += __shfl_xor(sum, o);
            float inv = 1.0f / sum;
            #pragma unroll
            for (int tn = 0; tn < 4; ++tn)
                sP[i * 64 + tn * 16 + l15] = f2b(v[tn] * inv);
        }
    __syncthreads();

    // PV: A = P (64x64), B = v (64x32)
    f32x4 accO[4][2] = {};
    #pragma unroll
    for (int ks = 0; ks < 2; ++ks) {
        short8 bV[2];
        #pragma unroll
        for (int tn = 0; tn < 2; ++tn)
            #pragma unroll
            for (int jj = 0; jj < 8; ++jj)
                bV[tn][jj] = (short)sV[(ks * 32 + lq * 8 + jj) * 32 + tn * 16 + l15];
        #pragma unroll
        for (int tm = 0; tm < 4; ++tm) {
            short8 aP = *(const short8*)&sP[(tm * 16 + l15) * 64 + ks * 32 + lq * 8];
            accO[tm][0] = MFMA16(aP, bV[0], accO[tm][0]);
            accO[tm][1] = MFMA16(aP, bV[1], accO[tm][1]);
        }
    }

    // scatter back through reverse shift (same +4 mapping) into [token][C] bf16
    #pragma unroll
    for (int tm = 0; tm < 4; ++tm)
        #pragma unroll
        for (int r = 0; r < 4; ++r) {
            int i = tm * 16 + lq * 4 + r;
            int hh = (wy * 8 + (i >> 3) + 4) & 63, ww = (wx * 8 + (i & 7) + 4) & 63;
            size_t rowo = ((size_t)b * 4096 + hh * 64 + ww) * 256 + h * 32;
            outb[rowo + l15] = f2b(accO[tm][0][r]);
            outb[rowo + 16 + l15] = f2b(accO[tm][1][r]);
        }
}

// ---------------- launcher ----------------

extern "C" void kernel_launch(void* const* d_in, const int* in_sizes, int n_in,
                              void* d_out, int out_size, void* d_ws, size_t ws_size,
                              hipStream_t stream) {
    (void)in_sizes; (void)n_in; (void)out_size; (void)ws_size;
    const float* x      = (const float*)d_in[0];
    const float* qkv_w  = (const float*)d_in[1];
    const float* q_bias = (const float*)d_in[2];
    const float* v_bias = (const float*)d_in[3];
    const float* lscale = (const float*)d_in[4];
    const float* cpb_w1 = (const float*)d_in[5];
    const float* cpb_b1 = (const float*)d_in[6];
    const float* cpb_w2 = (const float*)d_in[7];
    const float* proj_w = (const float*)d_in[8];
    const float* proj_b = (const float*)d_in[9];
    const float* n1g    = (const float*)d_in[10];
    const float* n1b    = (const float*)d_in[11];
    const float* fc1_w  = (const float*)d_in[12];
    const float* fc1_b  = (const float*)d_in[13];
    const float* fc2_w  = (const float*)d_in[14];
    const float* fc2_b  = (const float*)d_in[15];
    const float* n2g    = (const float*)d_in[16];
    const float* n2b    = (const float*)d_in[17];

    char* ws = (char*)d_ws;
    // R1: qkv(201MB) -> h(268MB)
    unsigned short* R1 = (unsigned short*)(ws);
    // R2: x_bf16 -> attnout (67MB)
    unsigned short* R2 = (unsigned short*)(ws + 268435456);
    // R3: x1 (67MB)
    unsigned short* R3 = (unsigned short*)(ws + 335544320);
    unsigned short* qkv_wT = (unsigned short*)(ws + 402653184);   // 768x256
    unsigned short* proj_wT = (unsigned short*)(ws + 403046400);  // 256x256
    unsigned short* fc1_wT  = (unsigned short*)(ws + 403177472);  // 1024x256
    unsigned short* fc2_wT  = (unsigned short*)(ws + 403701760);  // 256x1024
    float* qkv_bias = (float*)(ws + 404226048);                   // 768
    float* biasT    = (float*)(ws + 404229120);                   // 8x64x64

    cvt_kernel<<<TOKS * 256 / 1024, 256, 0, stream>>>(x, R2, TOKS * 256);
    wt_kernel<<<(256 * 768 + 255) / 256, 256, 0, stream>>>(qkv_w, qkv_wT, 256, 768);
    wt_kernel<<<(256 * 256 + 255) / 256, 256, 0, stream>>>(proj_w, proj_wT, 256, 256);
    wt_kernel<<<(256 * 1024 + 255) / 256, 256, 0, stream>>>(fc1_w, fc1_wT, 256, 1024);
    wt_kernel<<<(1024 * 256 + 255) / 256, 256, 0, stream>>>(fc2_w, fc2_wT, 1024, 256);
    cpb_kernel<<<8, 256, 0, stream>>>(cpb_w1, cpb_b1, cpb_w2, q_bias, v_bias, biasT, qkv_bias);

    // qkv: M=TOKS, N=768, K=256
    gemm_bt<1, 6, 256><<<dim3(6, TOKS / 128), 256, 0, stream>>>(R2, qkv_wT, qkv_bias, R1, 768);
    attn_kernel<<<16384, 64, 0, stream>>>(R1, biasT, lscale, R2);
    // proj GEMM + LN1 + f32 residual -> x1 (bf16)
    gemm_ln<1, 256><<<TOKS / 64, 256, 0, stream>>>(R2, proj_wT, proj_b, x, nullptr,
                                                   n1g, n1b, R3, nullptr);
    // fc1 GEMM + fast gelu -> h (bf16)
    gemm_bt<2, 8, 256><<<dim3(8, TOKS / 128), 256, 0, stream>>>(R3, fc1_wT, fc1_b, R1, 1024);
    // fc2 GEMM + LN2 + bf16 residual -> d_out (f32)
    gemm_ln<2, 1024><<<TOKS / 64, 256, 0, stream>>>(R1, fc2_wT, fc2_b, nullptr, R3,
                                                    n2g, n2b, nullptr, (float*)d_out);
}

// Round 6
// 923.549 us; speedup vs baseline: 1.3671x; 1.3671x over previous
//
#include <hip/hip_runtime.h>

// SwinV2 block, MI355X. All heavy math in bf16 MFMA (f32 accum).
// Pipeline: cvt(x) -> wT x4 -> cpb -> GEMM qkv -> attn -> GEMM proj+LN1 ->
//           GEMM fc1(gelu) -> GEMM fc2+LN2 -> d_out (f32).
// R4 (2-phase LDS-pipelined GEMMs) = 927us baseline; R5/R6/R7 structure
// experiments all regressed -> GEMMs restored to R4 verbatim.
// R8: attn rework only: (a) Q/K fragments loaded global->register with
//     in-register L2 normalize (no sQ/sK LDS, no barriers for QK^T);
//     (b) V stored transposed + XOR-swizzled so PV's B-operand is 4
//     ds_read_b128 (was 32 scalar ds_read_u16), 2-way conflict = free;
//     (c) LDS 20KB -> 12KB => 13 blocks/CU (was 8); single __syncthreads.

#define TOKS 131072            // B * H * W
#define LOGIT_MAX 4.60517018598809136804f

typedef __attribute__((ext_vector_type(8))) short short8;
typedef __attribute__((ext_vector_type(4))) float f32x4;

__device__ __forceinline__ float b2f(unsigned short s) {
    union { unsigned int u; float f; } x; x.u = ((unsigned int)s) << 16; return x.f;
}
__device__ __forceinline__ unsigned short f2b(float f) {
    union { float f; unsigned int u; } x; x.f = f;
    unsigned int r = x.u + 0x7fffu + ((x.u >> 16) & 1u);  // RNE
    return (unsigned short)(r >> 16);
}

#define MFMA16(a, b, c) __builtin_amdgcn_mfma_f32_16x16x32_bf16((a), (b), (c), 0, 0, 0)

// async global->LDS, 16B/lane; LDS dst = uniform base + lane*16
#define GLOAD_LDS16(g, l)                                                      \
    __builtin_amdgcn_global_load_lds(                                          \
        (const __attribute__((address_space(1))) void*)(g),                    \
        (__attribute__((address_space(3))) void*)(l), 16, 0, 0)

// ---------------- prep kernels ----------------

__global__ __launch_bounds__(256) void cvt_kernel(const float* __restrict__ in,
                                                  unsigned short* __restrict__ out, int n) {
    int i = (blockIdx.x * 256 + threadIdx.x) * 4;
    if (i >= n) return;
    float4 v = *(const float4*)(in + i);
    ushort4 o;
    o.x = f2b(v.x); o.y = f2b(v.y); o.z = f2b(v.z); o.w = f2b(v.w);
    *(ushort4*)(out + i) = o;
}

// dst[n*K + k] = bf16(src[k*N + n])   (src is K x N row-major, dst is N x K)
__global__ __launch_bounds__(256) void wt_kernel(const float* __restrict__ src,
                                                 unsigned short* __restrict__ dst,
                                                 int K, int N) {
    int idx = blockIdx.x * 256 + threadIdx.x;
    if (idx >= K * N) return;
    int n = idx / K, k = idx - n * K;
    dst[idx] = f2b(src[(size_t)k * N + n]);
}

__device__ __forceinline__ float cpb_coord(int d) {
    float t = (float)d * (8.0f / 7.0f);
    float a = log2f(fabsf(t) + 1.0f) * (1.0f / 3.0f);   // log2(8)=3
    return t < 0.0f ? -a : a;
}

// biasT[h][i][j] = 16*sigmoid( cpb_mlp(rel_coords(i,j))[h] );  qkv_bias[768]
__global__ __launch_bounds__(256) void cpb_kernel(
    const float* __restrict__ w1, const float* __restrict__ b1, const float* __restrict__ w2,
    const float* __restrict__ qb, const float* __restrict__ vb,
    float* __restrict__ biasT, float* __restrict__ qkv_bias)
{
    __shared__ float tbl[225];
    int h = blockIdx.x, t = threadIdx.x;
    if (t < 225) {
        float r0 = cpb_coord(t / 15 - 7), r1 = cpb_coord(t % 15 - 7);
        float acc = 0.f;
        for (int j = 0; j < 512; ++j) {
            float hid = fmaxf(r0 * w1[j] + r1 * w1[512 + j] + b1[j], 0.f);
            acc += hid * w2[j * 8 + h];
        }
        tbl[t] = acc;
    }
    __syncthreads();
    for (int o = t; o < 4096; o += 256) {
        int i = o >> 6, j = o & 63;
        int idx = ((i >> 3) - (j >> 3) + 7) * 15 + ((i & 7) - (j & 7) + 7);
        biasT[h * 4096 + o] = 16.0f / (1.0f + __expf(-tbl[idx]));
    }
    if (h == 0)
        for (int n = t; n < 768; n += 256)
            qkv_bias[n] = n < 256 ? qb[n] : (n < 512 ? 0.f : vb[n - 512]);
}

// ---------------- tiled bf16 MFMA GEMM: C = A(MxK) * Bt(NxK)^T + bias ----------------
// 2-phase pipelined: double-buffered LDS, counted vmcnt, raw barriers. (R4, proven)
// EPI 0: bf16 row-major out.  EPI 1: qkv scatter.  EPI 2: fast gelu, bf16 out.
template<int EPI, int GX>
__global__ __launch_bounds__(256) void gemm_bt(
    const unsigned short* __restrict__ A, const unsigned short* __restrict__ Bt,
    const float* __restrict__ bias, unsigned short* __restrict__ out,
    int M, int N, int K)
{
    __shared__ __align__(16) unsigned short sA[2][128 * 32];
    __shared__ __align__(16) unsigned short sB[2][128 * 32];
    const int tid = threadIdx.x;
    const int lane = tid & 63;
    const int wave = tid >> 6;
    const int wm = (wave >> 1) * 64, wn = (wave & 1) * 64;
    // XCD-bijective swizzle (nwg % 8 == 0 for all our grids)
    const int nwg = GX * (int)gridDim.y;
    int flat = (int)(blockIdx.y * GX + blockIdx.x);
    flat = (flat & 7) * (nwg >> 3) + (flat >> 3);
    const int bx = flat % GX;
    const int by = flat / GX;
    const int m0 = by * 128, n0 = bx * 128;
    const int l15 = lane & 15, lq = lane >> 4;
    const int r0 = tid >> 2, c0 = (tid & 3) << 3;

    const unsigned short* pA0 = A + (size_t)(m0 + r0) * K + c0;
    const unsigned short* pA1 = A + (size_t)(m0 + r0 + 64) * K + c0;
    const unsigned short* pB0 = Bt + (size_t)(n0 + r0) * K + c0;
    const unsigned short* pB1 = Bt + (size_t)(n0 + r0 + 64) * K + c0;

    auto stage = [&](int buf, int k0) {
        unsigned short* a = &sA[buf][wave * 512];
        unsigned short* b = &sB[buf][wave * 512];
        GLOAD_LDS16(pA0 + k0, a);
        GLOAD_LDS16(pA1 + k0, a + 2048);
        GLOAD_LDS16(pB0 + k0, b);
        GLOAD_LDS16(pB1 + k0, b + 2048);
    };

    f32x4 acc[4][4] = {};
    auto compute = [&](int buf) {
        short8 af[4], bw[4];
        #pragma unroll
        for (int t = 0; t < 4; ++t) {
            af[t] = *(const short8*)&sA[buf][(wm + t * 16 + l15) * 32 + lq * 8];
            bw[t] = *(const short8*)&sB[buf][(wn + t * 16 + l15) * 32 + lq * 8];
        }
        #pragma unroll
        for (int tm = 0; tm < 4; ++tm)
            #pragma unroll
            for (int tn = 0; tn < 4; ++tn)
                acc[tm][tn] = MFMA16(af[tm], bw[tn], acc[tm][tn]);
    };

    const int nt = K >> 5;
    stage(0, 0);
    for (int t = 0; t < nt - 1; ++t) {
        stage((t & 1) ^ 1, (t + 1) << 5);                 // next tile stays in flight
        asm volatile("s_waitcnt vmcnt(4)" ::: "memory");  // tile t staged
        __builtin_amdgcn_s_barrier();
        asm volatile("" ::: "memory");
        compute(t & 1);
        asm volatile("s_waitcnt lgkmcnt(0)" ::: "memory"); // ds_reads of buf done
        __builtin_amdgcn_s_barrier();
    }
    asm volatile("s_waitcnt vmcnt(0)" ::: "memory");
    __builtin_amdgcn_s_barrier();
    asm volatile("" ::: "memory");
    compute((nt - 1) & 1);

    float bv[4];
    #pragma unroll
    for (int tn = 0; tn < 4; ++tn) bv[tn] = bias[n0 + wn + tn * 16 + l15];

    #pragma unroll
    for (int tm = 0; tm < 4; ++tm)
        #pragma unroll
        for (int tn = 0; tn < 4; ++tn)
            #pragma unroll
            for (int r = 0; r < 4; ++r) {
                int gm = m0 + wm + tm * 16 + lq * 4 + r;
                int gn = n0 + wn + tn * 16 + l15;
                float v = acc[tm][tn][r] + bv[tn];
                if constexpr (EPI == 2) {
                    // gelu(v) ~= v * sigmoid(1.59577v + 0.0713548 v^3); |err|<~1e-3
                    float e = __expf(v * fmaf(-0.0713548162972754f, v * v,
                                              -1.5957691216057308f));
                    v = v * __builtin_amdgcn_rcpf(1.0f + e);
                }
                if constexpr (EPI == 1) {
                    int s = gn >> 8, hd = gn & 255;
                    out[((size_t)(s * 8 + (hd >> 5)) * TOKS + gm) * 32 + (hd & 31)] = f2b(v);
                } else {
                    out[(size_t)gm * N + gn] = f2b(v);
                }
            }
}

// ---------------- fused GEMM + LayerNorm + residual ----------------
// 64x256 output tile (full channel row), 4 waves 1x4, 2-phase pipelined. (R4)
// MODE 1: outb = bf16( residf_f32 + LN(A@Bt^T + bias) )   (x1 = x + LN(proj))
// MODE 2: outf = f32(residb_bf16) + LN(A@Bt^T + bias)     (d_out = x1 + LN(h2))
template<int MODE>
__global__ __launch_bounds__(256) void gemm_ln(
    const unsigned short* __restrict__ A, const unsigned short* __restrict__ Bt,
    const float* __restrict__ bias,
    const float* __restrict__ residf, const unsigned short* __restrict__ residb,
    const float* __restrict__ lng, const float* __restrict__ lnb,
    unsigned short* __restrict__ outb, float* __restrict__ outf, int K)
{
    __shared__ __align__(16) unsigned short sA[2][64 * 32];
    __shared__ __align__(16) unsigned short sB[2][256 * 32];
    const int tid = threadIdx.x;
    const int lane = tid & 63;
    const int wave = tid >> 6;
    const int wn = wave * 64;
    const int m0 = blockIdx.x * 64;
    const int l15 = lane & 15, lq = lane >> 4;
    const int r0 = tid >> 2, c0 = (tid & 3) << 3;

    const unsigned short* pA  = A + (size_t)(m0 + r0) * K + c0;
    const unsigned short* pB0 = Bt + (size_t)r0 * K + c0;
    const unsigned short* pB1 = pB0 + (size_t)64 * K;
    const unsigned short* pB2 = pB0 + (size_t)128 * K;
    const unsigned short* pB3 = pB0 + (size_t)192 * K;

    auto stage = [&](int buf, int k0) {
        unsigned short* a = &sA[buf][wave * 512];
        unsigned short* b = &sB[buf][wave * 512];
        GLOAD_LDS16(pA + k0, a);
        GLOAD_LDS16(pB0 + k0, b);
        GLOAD_LDS16(pB1 + k0, b + 2048);
        GLOAD_LDS16(pB2 + k0, b + 4096);
        GLOAD_LDS16(pB3 + k0, b + 6144);
    };

    f32x4 acc[4][4] = {};
    auto compute = [&](int buf) {
        short8 af[4], bw[4];
        #pragma unroll
        for (int t = 0; t < 4; ++t) {
            af[t] = *(const short8*)&sA[buf][(t * 16 + l15) * 32 + lq * 8];
            bw[t] = *(const short8*)&sB[buf][(wn + t * 16 + l15) * 32 + lq * 8];
        }
        #pragma unroll
        for (int tm = 0; tm < 4; ++tm)
            #pragma unroll
            for (int tn = 0; tn < 4; ++tn)
                acc[tm][tn] = MFMA16(af[tm], bw[tn], acc[tm][tn]);
    };

    const int nt = K >> 5;
    stage(0, 0);
    for (int t = 0; t < nt - 1; ++t) {
        stage((t & 1) ^ 1, (t + 1) << 5);
        asm volatile("s_waitcnt vmcnt(5)" ::: "memory");
        __builtin_amdgcn_s_barrier();
        asm volatile("" ::: "memory");
        compute(t & 1);
        asm volatile("s_waitcnt lgkmcnt(0)" ::: "memory");
        __builtin_amdgcn_s_barrier();
    }
    asm volatile("s_waitcnt vmcnt(0)" ::: "memory");
    __builtin_amdgcn_s_barrier();
    asm volatile("" ::: "memory");
    compute((nt - 1) & 1);
    asm volatile("s_waitcnt lgkmcnt(0)" ::: "memory");
    __builtin_amdgcn_s_barrier();                 // all waves done with LDS before overlay

    float bv[4], gv[4], ev[4];
    #pragma unroll
    for (int tn = 0; tn < 4; ++tn) {
        int gn = wn + tn * 16 + l15;
        bv[tn] = bias[gn]; gv[tn] = lng[gn]; ev[tn] = lnb[gn];
    }

    // cross-wave row sums via LDS (overlays sA; staging fully drained)
    float* sums = (float*)&sA[0][0];          // [64][4]
    float* sqs  = (float*)&sA[0][0] + 256;    // [64][4]
    #pragma unroll
    for (int tm = 0; tm < 4; ++tm)
        #pragma unroll
        for (int r = 0; r < 4; ++r) {
            int rl = tm * 16 + lq * 4 + r;
            float s = 0.f, q = 0.f;
            #pragma unroll
            for (int tn = 0; tn < 4; ++tn) {
                float v = acc[tm][tn][r] + bv[tn];
                s += v; q += v * v;
            }
            #pragma unroll
            for (int o = 1; o < 16; o <<= 1) { s += __shfl_xor(s, o); q += __shfl_xor(q, o); }
            if (l15 == 0) { sums[rl * 4 + wave] = s; sqs[rl * 4 + wave] = q; }
        }
    __syncthreads();

    #pragma unroll
    for (int tm = 0; tm < 4; ++tm)
        #pragma unroll
        for (int r = 0; r < 4; ++r) {
            int rl = tm * 16 + lq * 4 + r;
            float s = sums[rl * 4] + sums[rl * 4 + 1] + sums[rl * 4 + 2] + sums[rl * 4 + 3];
            float q = sqs[rl * 4] + sqs[rl * 4 + 1] + sqs[rl * 4 + 2] + sqs[rl * 4 + 3];
            float mu = s * (1.0f / 256.0f);
            float rs = rsqrtf(q * (1.0f / 256.0f) - mu * mu + 1e-5f);
            size_t rowo = (size_t)(m0 + rl) * 256;
            #pragma unroll
            for (int tn = 0; tn < 4; ++tn) {
                int gn = wn + tn * 16 + l15;
                float v = acc[tm][tn][r] + bv[tn];
                float nv = (v - mu) * rs * gv[tn] + ev[tn];
                if constexpr (MODE == 1)
                    outb[rowo + gn] = f2b(residf[rowo + gn] + nv);
                else
                    outf[rowo + gn] = b2f(residb[rowo + gn]) + nv;
            }
        }
}

// ---------------- attention: one wave per (window, head) ----------------
// R8: Q/K fragments global->register with in-register L2 normalize; V stored
// transposed+XOR-swizzled in LDS for vectorized PV reads; single barrier.

__device__ __forceinline__ int regid(int wy, int wx, int t) {
    int y = wy * 8 + (t >> 3), x = wx * 8 + (t & 7);
    int ry = (y < 56) ? 0 : (y < 60 ? 1 : 2);
    int rx = (x < 56) ? 0 : (x < 60 ? 1 : 2);
    return ry * 3 + rx;
}

__global__ __launch_bounds__(64) void attn_kernel(
    const unsigned short* __restrict__ qkv, const float* __restrict__ biasT,
    const float* __restrict__ ls, unsigned short* __restrict__ outb)
{
    __shared__ __align__(16) unsigned short sVT[32 * 64];  // V^T, XOR-swizzled (4KB)
    __shared__ __align__(16) unsigned short sP[64 * 64];   // softmax probs (8KB)

    const int lane = threadIdx.x;
    const int h = blockIdx.x & 7;
    const int win = blockIdx.x >> 3;
    const int b = win >> 6;
    const int wy = (win >> 3) & 7, wx = win & 7;
    const int l15 = lane & 15, lq = lane >> 4;
    const size_t plane = (size_t)TOKS * 32;
    const size_t base = (size_t)b * 4096;

    union U { uint4 u; unsigned short s[8]; };

    // V: lane = window token (shift-mapped), contiguous 32 elems
    U vld[4];
    {
        int hh = (wy * 8 + (lane >> 3) + 4) & 63, ww = (wx * 8 + (lane & 7) + 4) & 63;
        const unsigned short* vp = qkv + (size_t)(16 + h) * plane + (base + hh * 64 + ww) * 32;
        #pragma unroll
        for (int c = 0; c < 4; ++c) vld[c].u = *(const uint4*)(vp + c * 8);
    }

    // Q,K: fragment-direct loads; row i = t*16+l15, elems lq*8..lq*8+7
    U qld[4], kld[4];
    #pragma unroll
    for (int t = 0; t < 4; ++t) {
        int i = t * 16 + l15;
        int hh = (wy * 8 + (i >> 3) + 4) & 63, ww = (wx * 8 + (i & 7) + 4) & 63;
        size_t tok = base + hh * 64 + ww;
        qld[t].u = *(const uint4*)(qkv + (size_t)h * plane + tok * 32 + lq * 8);
        kld[t].u = *(const uint4*)(qkv + (size_t)(8 + h) * plane + tok * 32 + lq * 8);
    }

    // store V^T: sVT[d*64 + (tok ^ ((d&7)<<3))] = V[tok][d]; banks 2-way (free)
    #pragma unroll
    for (int c = 0; c < 4; ++c)
        #pragma unroll
        for (int j = 0; j < 8; ++j)
            sVT[(c * 8 + j) * 64 + (lane ^ (j << 3))] = vld[c].s[j];

    // in-register L2 normalize of Q,K rows (row = 4 lanes sharing l15: xor 16,32)
    short8 aQ[4], bK[4];
    #pragma unroll
    for (int t = 0; t < 4; ++t) {
        float qf[8], kf[8]; float qs = 0.f, kss = 0.f;
        #pragma unroll
        for (int j = 0; j < 8; ++j) {
            qf[j] = b2f(qld[t].s[j]); qs += qf[j] * qf[j];
            kf[j] = b2f(kld[t].s[j]); kss += kf[j] * kf[j];
        }
        qs += __shfl_xor(qs, 16);  qs += __shfl_xor(qs, 32);
        kss += __shfl_xor(kss, 16); kss += __shfl_xor(kss, 32);
        float qn = rsqrtf(fmaxf(qs, 1e-12f)), kn = rsqrtf(fmaxf(kss, 1e-12f));
        #pragma unroll
        for (int j = 0; j < 8; ++j) {
            aQ[t][j] = (short)f2b(qf[j] * qn);
            bK[t][j] = (short)f2b(kf[j] * kn);
        }
    }

    // QK^T (all register operands, no barrier needed)
    f32x4 acc[4][4] = {};
    #pragma unroll
    for (int tm = 0; tm < 4; ++tm)
        #pragma unroll
        for (int tn = 0; tn < 4; ++tn)
            acc[tm][tn] = MFMA16(aQ[tm], bK[tn], acc[tm][tn]);

    float scale = __expf(fminf(ls[h], LOGIT_MAX));

    // scale + cpb-bias + shift-mask + softmax (rows: (lq,r,tm); cols: (tn,l15))
    #pragma unroll
    for (int tm = 0; tm < 4; ++tm)
        #pragma unroll
        for (int r = 0; r < 4; ++r) {
            int i = tm * 16 + lq * 4 + r;
            int ri = regid(wy, wx, i);
            float v[4];
            #pragma unroll
            for (int tn = 0; tn < 4; ++tn) {
                int j = tn * 16 + l15;
                float sc = acc[tm][tn][r] * scale + biasT[h * 4096 + i * 64 + j];
                if (ri != regid(wy, wx, j)) sc -= 100.f;
                v[tn] = sc;
            }
            float m = fmaxf(fmaxf(v[0], v[1]), fmaxf(v[2], v[3]));
            #pragma unroll
            for (int o = 1; o < 16; o <<= 1) m = fmaxf(m, __shfl_xor(m, o));
            float sum = 0.f;
            #pragma unroll
            for (int tn = 0; tn < 4; ++tn) { v[tn] = __expf(v[tn] - m); sum += v[tn]; }
            #pragma unroll
            for (int o = 1; o < 16; o <<= 1) sum += __shfl_xor(sum, o);
            float inv = 1.0f / sum;
            #pragma unroll
            for (int tn = 0; tn < 4; ++tn)
                sP[i * 64 + tn * 16 + l15] = f2b(v[tn] * inv);
        }
    __syncthreads();   // sVT + sP visible to all lanes

    // PV: A = P (64x64), B = V (64x32) via swizzled V^T vector reads
    f32x4 accO[4][2] = {};
    #pragma unroll
    for (int ks = 0; ks < 2; ++ks) {
        short8 bV[2];
        #pragma unroll
        for (int tn = 0; tn < 2; ++tn) {
            int d = tn * 16 + l15;
            int t8 = (ks * 32 + lq * 8) ^ ((l15 & 7) << 3);
            bV[tn] = *(const short8*)&sVT[d * 64 + t8];
        }
        #pragma unroll
        for (int tm = 0; tm < 4; ++tm) {
            short8 aP = *(const short8*)&sP[(tm * 16 + l15) * 64 + ks * 32 + lq * 8];
            accO[tm][0] = MFMA16(aP, bV[0], accO[tm][0]);
            accO[tm][1] = MFMA16(aP, bV[1], accO[tm][1]);
        }
    }

    // scatter back through reverse shift (same +4 mapping) into [token][C] bf16
    #pragma unroll
    for (int tm = 0; tm < 4; ++tm)
        #pragma unroll
        for (int r = 0; r < 4; ++r) {
            int i = tm * 16 + lq * 4 + r;
            int hh = (wy * 8 + (i >> 3) + 4) & 63, ww = (wx * 8 + (i & 7) + 4) & 63;
            size_t rowo = (base + hh * 64 + ww) * 256 + h * 32;
            outb[rowo + l15] = f2b(accO[tm][0][r]);
            outb[rowo + 16 + l15] = f2b(accO[tm][1][r]);
        }
}

// ---------------- launcher ----------------

extern "C" void kernel_launch(void* const* d_in, const int* in_sizes, int n_in,
                              void* d_out, int out_size, void* d_ws, size_t ws_size,
                              hipStream_t stream) {
    (void)in_sizes; (void)n_in; (void)out_size; (void)ws_size;
    const float* x      = (const float*)d_in[0];
    const float* qkv_w  = (const float*)d_in[1];
    const float* q_bias = (const float*)d_in[2];
    const float* v_bias = (const float*)d_in[3];
    const float* lscale = (const float*)d_in[4];
    const float* cpb_w1 = (const float*)d_in[5];
    const float* cpb_b1 = (const float*)d_in[6];
    const float* cpb_w2 = (const float*)d_in[7];
    const float* proj_w = (const float*)d_in[8];
    const float* proj_b = (const float*)d_in[9];
    const float* n1g    = (const float*)d_in[10];
    const float* n1b    = (const float*)d_in[11];
    const float* fc1_w  = (const float*)d_in[12];
    const float* fc1_b  = (const float*)d_in[13];
    const float* fc2_w  = (const float*)d_in[14];
    const float* fc2_b  = (const float*)d_in[15];
    const float* n2g    = (const float*)d_in[16];
    const float* n2b    = (const float*)d_in[17];

    char* ws = (char*)d_ws;
    // R1: qkv(201MB) -> h(268MB)
    unsigned short* R1 = (unsigned short*)(ws);
    // R2: x_bf16 -> attnout (67MB)
    unsigned short* R2 = (unsigned short*)(ws + 268435456);
    // R3: x1 (67MB)
    unsigned short* R3 = (unsigned short*)(ws + 335544320);
    unsigned short* qkv_wT = (unsigned short*)(ws + 402653184);   // 768x256
    unsigned short* proj_wT = (unsigned short*)(ws + 403046400);  // 256x256
    unsigned short* fc1_wT  = (unsigned short*)(ws + 403177472);  // 1024x256
    unsigned short* fc2_wT  = (unsigned short*)(ws + 403701760);  // 256x1024
    float* qkv_bias = (float*)(ws + 404226048);                   // 768
    float* biasT    = (float*)(ws + 404229120);                   // 8x64x64

    cvt_kernel<<<TOKS * 256 / 1024, 256, 0, stream>>>(x, R2, TOKS * 256);
    wt_kernel<<<(256 * 768 + 255) / 256, 256, 0, stream>>>(qkv_w, qkv_wT, 256, 768);
    wt_kernel<<<(256 * 256 + 255) / 256, 256, 0, stream>>>(proj_w, proj_wT, 256, 256);
    wt_kernel<<<(256 * 1024 + 255) / 256, 256, 0, stream>>>(fc1_w, fc1_wT, 256, 1024);
    wt_kernel<<<(1024 * 256 + 255) / 256, 256, 0, stream>>>(fc2_w, fc2_wT, 1024, 256);
    cpb_kernel<<<8, 256, 0, stream>>>(cpb_w1, cpb_b1, cpb_w2, q_bias, v_bias, biasT, qkv_bias);

    gemm_bt<1, 6><<<dim3(6, TOKS / 128), 256, 0, stream>>>(R2, qkv_wT, qkv_bias, R1, TOKS, 768, 256);
    attn_kernel<<<16384, 64, 0, stream>>>(R1, biasT, lscale, R2);
    // proj GEMM + LN1 + f32 residual -> x1 (bf16)
    gemm_ln<1><<<TOKS / 64, 256, 0, stream>>>(R2, proj_wT, proj_b, x, nullptr,
                                              n1g, n1b, R3, nullptr, 256);
    // fc1 GEMM + fast gelu -> h (bf16)
    gemm_bt<2, 8><<<dim3(8, TOKS / 128), 256, 0, stream>>>(R3, fc1_wT, fc1_b, R1, TOKS, 1024, 256);
    // fc2 GEMM + LN2 + bf16 residual -> d_out (f32)
    gemm_ln<2><<<TOKS / 64, 256, 0, stream>>>(R1, fc2_wT, fc2_b, nullptr, R3,
                                              n2g, n2b, nullptr, (float*)d_out, 1024);
}